// Round 2
// baseline (379.757 us; speedup 1.0000x reference)
//
#include <hip/hip_runtime.h>
#include <hip/hip_bf16.h>
#include <stdint.h>

typedef __attribute__((ext_vector_type(8))) short short8;
typedef __attribute__((ext_vector_type(4))) float f32x4;
typedef __attribute__((ext_vector_type(4))) unsigned short ushort4v;

#define MFMA_BF16(a,b,c) __builtin_amdgcn_mfma_f32_16x16x32_bf16((a),(b),(c),0,0,0)

static __device__ __forceinline__ unsigned short f2bf(float f){
  union { float fv; unsigned int u; } c; c.fv = f;
  unsigned int u = c.u;
  return (unsigned short)((u + 0x7fffu + ((u >> 16) & 1u)) >> 16);
}

static __device__ __forceinline__ void gload_lds16(const void* g, void* l){
  __builtin_amdgcn_global_load_lds(
      (const __attribute__((address_space(1))) void*)g,
      (__attribute__((address_space(3))) void*)l, 16, 0, 0);
}

static __device__ __forceinline__ float wred_max(float v){
  #pragma unroll
  for (int m = 32; m; m >>= 1) v = fmaxf(v, __shfl_xor(v, m, 64));
  return v;
}
static __device__ __forceinline__ float wred_sum(float v){
  #pragma unroll
  for (int m = 32; m; m >>= 1) v += __shfl_xor(v, m, 64);
  return v;
}

// ---------------- conversion kernels ----------------
__global__ __launch_bounds__(256) void cvt_x_kernel(const float* __restrict__ x,
                                                    unsigned short* __restrict__ o){
  int i = blockIdx.x * 256 + threadIdx.x;          // 2,097,152 float4s total
  float4 f = ((const float4*)x)[i];
  ushort4v r;
  r[0] = f2bf(f.x); r[1] = f2bf(f.y); r[2] = f2bf(f.z); r[3] = f2bf(f.w);
  ((ushort4v*)o)[i] = r;
}

__global__ __launch_bounds__(256) void cvt_w_kernel(const float* __restrict__ Wq,
                                                    const float* __restrict__ Wk,
                                                    const float* __restrict__ Wv,
                                                    const float* __restrict__ Ws,
                                                    unsigned short* __restrict__ B){
  int i = blockIdx.x * 256 + threadIdx.x;          // 1,048,576 float4s total
  int which = i >> 18;                              // 262144 float4s per matrix
  const float* src = (which == 0) ? Wq : (which == 1) ? Wk : (which == 2) ? Wv : Ws;
  float4 f = ((const float4*)src)[i & 262143];
  ushort4v r;
  r[0] = f2bf(f.x); r[1] = f2bf(f.y); r[2] = f2bf(f.z); r[3] = f2bf(f.w);
  ((ushort4v*)B)[i] = r;
}

__global__ void wb_prep_kernel(const float* __restrict__ Wb,
                               float* __restrict__ wba, float* __restrict__ wbb){
  int e = blockIdx.x * 256 + threadIdx.x;
  if (e < 1024){
    wba[e] = Wb[e]        + Wb[2048 + e];
    wbb[e] = Wb[1024 + e] - Wb[2048 + e];
  }
}

// ---------------- fused projection GEMM ----------------
// C(8192 x 4096) = Xbf(8192 x 1024) @ Bmat(4096 x 1024)^T; epilogue scatters to
// q/k (b,h,s,d) bf16, v transposed (b,h,d,s) bf16, r (t,e) fp32.
__global__ __launch_bounds__(256, 2) void gemm_proj_kernel(
    const unsigned short* __restrict__ X, const unsigned short* __restrict__ B,
    unsigned short* __restrict__ qb, unsigned short* __restrict__ kb,
    unsigned short* __restrict__ vT, float* __restrict__ rb)
{
  __shared__ unsigned short As[128 * 32];
  __shared__ unsigned short Bs[128 * 32];
  const int tid = threadIdx.x;
  const int w = tid >> 6, l = tid & 63;
  const int lr = l & 15, lq = l >> 4;
  const int wr = w >> 1, wc = w & 1;
  const int m0 = (blockIdx.x >> 5) * 128;
  const int n0 = (blockIdx.x & 31) * 128;
  f32x4 acc[4][4] = {};

  for (int k0 = 0; k0 < 1024; k0 += 32){
    #pragma unroll
    for (int i = 0; i < 2; i++){
      int c = i * 256 + tid;                       // 16B chunk id, row = c>>2, colgrp = c&3
      gload_lds16(X + (size_t)(m0 + (c >> 2)) * 1024 + k0 + (c & 3) * 8,
                  As + (i * 256 + w * 64) * 8);
      gload_lds16(B + (size_t)(n0 + (c >> 2)) * 1024 + k0 + (c & 3) * 8,
                  Bs + (i * 256 + w * 64) * 8);
    }
    __syncthreads();
    short8 av[4], bv[4];
    #pragma unroll
    for (int mf = 0; mf < 4; mf++)
      av[mf] = *(const short8*)(As + (wr * 64 + mf * 16 + lr) * 32 + lq * 8);
    #pragma unroll
    for (int nf = 0; nf < 4; nf++)
      bv[nf] = *(const short8*)(Bs + (wc * 64 + nf * 16 + lr) * 32 + lq * 8);
    #pragma unroll
    for (int mf = 0; mf < 4; mf++)
      #pragma unroll
      for (int nf = 0; nf < 4; nf++)
        acc[mf][nf] = MFMA_BF16(av[mf], bv[nf], acc[mf][nf]);
    __syncthreads();
  }

  // epilogue: which output matrix (uniform per block: 128-col tile never straddles 1024)
  const int which = (n0 >> 10);
  #pragma unroll
  for (int mf = 0; mf < 4; mf++){
    #pragma unroll
    for (int nf = 0; nf < 4; nf++){
      const int col = n0 + wc * 64 + nf * 16 + lr;
      const int o = col & 1023;
      #pragma unroll
      for (int rg = 0; rg < 4; rg++){
        const int rowi = m0 + wr * 64 + mf * 16 + lq * 4 + rg;
        const float val = acc[mf][nf][rg];
        if (which == 3){
          rb[(size_t)rowi * 1024 + o] = val;
        } else {
          const int s = rowi >> 4, bb = rowi & 15;
          const int bh = bb * 16 + (o >> 6), d = o & 63;
          if (which == 0)      qb[((size_t)bh * 512 + s) * 64 + d] = f2bf(val);
          else if (which == 1) kb[((size_t)bh * 512 + s) * 64 + d] = f2bf(val);
          else                 vT[((size_t)bh * 64 + d) * 512 + s] = f2bf(val);
        }
      }
    }
  }
}

// ---------------- fused attention (double masked softmax) ----------------
__global__ __launch_bounds__(256, 3) void attn_kernel(
    const unsigned short* __restrict__ qg, const unsigned short* __restrict__ kg,
    const unsigned short* __restrict__ vt, const int* __restrict__ mask,
    const int* __restrict__ wmask, float* __restrict__ outp)
{
  __shared__ float sc[16 * 516];            // scores, padded stride
  __shared__ unsigned short al[16 * 520];   // final attn weights, bf16
  const int bid = blockIdx.x;
  const int qt = bid & 31, h = (bid >> 5) & 15, b = bid >> 9;
  const int bh = b * 16 + h;
  const int tid = threadIdx.x, w = tid >> 6, l = tid & 63;
  const int lr = l & 15, lq = l >> 4;
  const unsigned short* qp = qg + ((size_t)bh * 512 + qt * 16) * 64;
  const unsigned short* kp = kg + (size_t)bh * 512 * 64;
  const unsigned short* vp = vt + (size_t)bh * 64 * 512;

  // Phase A: S = q k^T * 0.125
  short8 qa0 = *(const short8*)(qp + lr * 64 + lq * 8);
  short8 qa1 = *(const short8*)(qp + lr * 64 + 32 + lq * 8);
  #pragma unroll
  for (int kf = 0; kf < 8; kf++){
    const int kc = w * 128 + kf * 16 + lr;
    short8 b0 = *(const short8*)(kp + kc * 64 + lq * 8);
    short8 b1 = *(const short8*)(kp + kc * 64 + 32 + lq * 8);
    f32x4 acc = {};
    acc = MFMA_BF16(qa0, b0, acc);
    acc = MFMA_BF16(qa1, b1, acc);
    #pragma unroll
    for (int rg = 0; rg < 4; rg++)
      sc[(lq * 4 + rg) * 516 + w * 128 + kf * 16 + lr] = acc[rg] * 0.125f;
  }
  __syncthreads();

  // Phase B: faithful double masked softmax, one wave per 4 rows
  for (int rr = 0; rr < 4; rr++){
    const int row = w * 4 + rr;
    const int qrow = qt * 16 + row;
    const int* mrow = mask  + ((size_t)b * 512 + qrow) * 512 + l * 8;
    const int* wrow = wmask + ((size_t)b * 512 + qrow) * 512 + l * 8;
    float s8[8];
    *(float4*)(&s8[0]) = *(const float4*)(&sc[row * 516 + l * 8]);
    *(float4*)(&s8[4]) = *(const float4*)(&sc[row * 516 + l * 8 + 4]);
    int4 ma = *(const int4*)(mrow);
    int4 mb2 = *(const int4*)(mrow + 4);
    int4 wa = *(const int4*)(wrow);
    int4 wc2 = *(const int4*)(wrow + 4);
    int m8[8]  = {ma.x, ma.y, ma.z, ma.w, mb2.x, mb2.y, mb2.z, mb2.w};
    int wm8[8] = {wa.x, wa.y, wa.z, wa.w, wc2.x, wc2.y, wc2.z, wc2.w};

    float v1[8]; float mx = -3.4e38f;
    #pragma unroll
    for (int j = 0; j < 8; j++){ v1[j] = m8[j] ? s8[j] : -9e15f; mx = fmaxf(mx, v1[j]); }
    const float M1 = wred_max(mx);
    float p1[8]; float z = 0.f;
    #pragma unroll
    for (int j = 0; j < 8; j++){ float e = expf(v1[j] - M1); p1[j] = m8[j] ? e : 0.f; z += p1[j]; }
    const float Z1 = wred_sum(z);
    const float i1 = 1.f / Z1;

    float v2[8]; float mx2 = -3.4e38f;
    #pragma unroll
    for (int j = 0; j < 8; j++){
      float pv = m8[j] ? p1[j] * i1 : 0.f;
      v2[j] = wm8[j] ? pv : -9e16f;
      mx2 = fmaxf(mx2, v2[j]);
    }
    const float M2 = wred_max(mx2);
    float p2[8]; float z2 = 0.f;
    #pragma unroll
    for (int j = 0; j < 8; j++){ float e = expf(v2[j] - M2); p2[j] = wm8[j] ? e : 0.f; z2 += p2[j]; }
    const float Z2 = wred_sum(z2);
    const float i2 = 1.f / Z2;
    float s2 = 0.f;
    #pragma unroll
    for (int j = 0; j < 8; j++){ p2[j] = wm8[j] ? p2[j] * i2 : 0.f; s2 += p2[j]; }
    const float S2 = wred_sum(s2);
    const float fin = 1.f / (S2 + 1e-10f);
    short8 o8;
    #pragma unroll
    for (int j = 0; j < 8; j++) o8[j] = (short)f2bf(p2[j] * fin);
    *(short8*)(al + row * 520 + l * 8) = o8;
  }
  __syncthreads();

  // Phase C: out = a @ V, K split over 4 waves
  f32x4 ao[4] = {};
  #pragma unroll
  for (int ks = 0; ks < 4; ks++){
    const int kc0 = w * 128 + ks * 32;
    short8 af = *(const short8*)(al + lr * 520 + kc0 + lq * 8);
    #pragma unroll
    for (int nf = 0; nf < 4; nf++){
      short8 vf = *(const short8*)(vp + (size_t)(nf * 16 + lr) * 512 + kc0 + lq * 8);
      ao[nf] = MFMA_BF16(af, vf, ao[nf]);
    }
  }
  float* part = sc;   // safe reuse: all reads of sc finished before the Phase-B barrier
  #pragma unroll
  for (int nf = 0; nf < 4; nf++)
    #pragma unroll
    for (int rg = 0; rg < 4; rg++)
      part[(w * 16 + lq * 4 + rg) * 64 + nf * 16 + lr] = ao[nf][rg];
  __syncthreads();
  for (int e = tid; e < 1024; e += 256){
    const int row = e >> 6, d = e & 63;
    float sum = part[row * 64 + d] + part[(16 + row) * 64 + d]
              + part[(32 + row) * 64 + d] + part[(48 + row) * 64 + d];
    outp[(((size_t)(qt * 16 + row)) * 16 + b) * 1024 + h * 64 + d] = sum;
  }
}

// ---------------- gate + mix ----------------
__global__ __launch_bounds__(256) void gate_kernel(
    const float* __restrict__ outp, const float* __restrict__ rb,
    const float* __restrict__ wba, const float* __restrict__ wbb,
    float* __restrict__ y)
{
  const int t = blockIdx.x * 4 + (threadIdx.x >> 6);
  const int l = threadIdx.x & 63;
  const float* o = outp + (size_t)t * 1024;
  const float* r = rb + (size_t)t * 1024;
  float ov[16], rv[16];
  float acc = 0.f;
  #pragma unroll
  for (int j = 0; j < 16; j++){
    const int e = j * 64 + l;
    ov[j] = o[e]; rv[j] = r[e];
    acc += ov[j] * wba[e] + rv[j] * wbb[e];
  }
  const float dot = wred_sum(acc);
  const float g = 1.f / (1.f + expf(-dot));
  float* yo = y + (size_t)t * 1024;
  #pragma unroll
  for (int j = 0; j < 16; j++){
    const int e = j * 64 + l;
    yo[e] = g * rv[j] + (1.f - g) * ov[j];
  }
}

// ---------------- launch ----------------
extern "C" void kernel_launch(void* const* d_in, const int* in_sizes, int n_in,
                              void* d_out, int out_size, void* d_ws, size_t ws_size,
                              hipStream_t stream)
{
  (void)in_sizes; (void)n_in; (void)out_size; (void)ws_size;
  const float* x   = (const float*)d_in[0];
  const int* mask  = (const int*)d_in[1];
  const int* wmask = (const int*)d_in[2];
  const float* Wq  = (const float*)d_in[3];
  const float* Wk  = (const float*)d_in[4];
  const float* Wv  = (const float*)d_in[5];
  const float* Ws  = (const float*)d_in[6];
  const float* Wb  = (const float*)d_in[7];

  char* ws = (char*)d_ws;
  unsigned short* xbf = (unsigned short*)ws; ws += 16777216;
  unsigned short* bm  = (unsigned short*)ws; ws += 8388608;
  unsigned short* qb  = (unsigned short*)ws; ws += 16777216;
  unsigned short* kb  = (unsigned short*)ws; ws += 16777216;
  unsigned short* vT  = (unsigned short*)ws; ws += 16777216;
  float* rb  = (float*)ws; ws += 33554432;
  float* op  = (float*)ws; ws += 33554432;
  float* wba = (float*)ws; ws += 4096;
  float* wbb = (float*)ws; ws += 4096;

  cvt_x_kernel<<<8192, 256, 0, stream>>>(x, xbf);
  cvt_w_kernel<<<4096, 256, 0, stream>>>(Wq, Wk, Wv, Ws, bm);
  wb_prep_kernel<<<4, 256, 0, stream>>>(Wb, wba, wbb);
  gemm_proj_kernel<<<2048, 256, 0, stream>>>(xbf, bm, qb, kb, vT, rb);
  attn_kernel<<<8192, 256, 0, stream>>>(qb, kb, vT, mask, wmask, op);
  gate_kernel<<<2048, 256, 0, stream>>>(op, rb, wba, wbb, (float*)d_out);
}